// Round 3
// baseline (28.077 us; speedup 1.0000x reference)
//
#include <hip/hip_runtime.h>

// ROI max-pool. feature_map: (1,256,50,50) f32, bboxes: (512,4) f32,
// out: (512,256,7,7) f32, scale = 1/16, pooled = 7.
//
// Kernel 1: NCHW -> NHWC transpose into d_ws (channels contiguous).
// Kernel 2: one block (8 waves) per box; wave-uniform bin loops; lane l
//           float4-loads channels 4l..4l+3 per cell; permuted LDS staging
//           (conflict-free stores AND reads); coalesced global writeback.

#define CC   256
#define HH   50
#define WW   50
#define NBOX 512
#define PP   7
#define SCL  (1.0f / 16.0f)
#define HW   (HH * WW)             // 2500
#define OUT_PER_BOX (CC * PP * PP) // 12544
#define NBIN (PP * PP)             // 49

// ---------- Kernel 1: (C, HW) -> (HW, C) transpose via 64x64 LDS tiles ----
__global__ __launch_bounds__(256) void transpose_kernel(
    const float* __restrict__ feat, float* __restrict__ featT)
{
    __shared__ float tile[64][65];          // +1 pad -> conflict-free column reads
    int tc = blockIdx.x & 3;                // channel tile 0..3
    int th = blockIdx.x >> 2;               // hw tile 0..39
    int c0 = tc * 64, h0 = th * 64;
    int lane = threadIdx.x & 63;
    int row4 = threadIdx.x >> 6;            // 0..3

    for (int it = 0; it < 16; ++it) {
        int r  = row4 + it * 4;             // c-row in tile
        int hw = h0 + lane;
        if (hw < HW)
            tile[r][lane] = feat[(c0 + r) * HW + hw];   // coalesced along hw
    }
    __syncthreads();
    for (int it = 0; it < 16; ++it) {
        int r  = row4 + it * 4;             // hw-row in tile
        int hw = h0 + r;
        if (hw < HW)
            featT[hw * CC + c0 + lane] = tile[lane][r]; // coalesced along c
    }
}

// ---------- Kernel 2: one block per box --------------------------------
__global__ __launch_bounds__(512) void pool_kernel(
    const float* __restrict__ featT,
    const float* __restrict__ boxes,
    float* __restrict__ out)
{
    // staging layout: res2[((c&3)*64 + (c>>2))*49 + pq]
    //   store (lane l, sub j, bin pq) -> (j*64 + l)*49 + pq
    //   lane-stride 49 words == 17 mod 32 -> bank permutation, conflict-free
    __shared__ float res2[OUT_PER_BOX];     // 50176 B
    int n    = blockIdx.x;
    int tid  = threadIdx.x;
    int wave = tid >> 6;
    int lane = tid & 63;

    const float* b = boxes + n * 4;
    int x1 = (int)floorf(b[0] * SCL + 0.5f);
    int y1 = (int)floorf(b[1] * SCL + 0.5f);
    int x2 = (int)floorf(b[2] * SCL + 0.5f);
    int y2 = (int)floorf(b[3] * SCL + 0.5f);
    int rw = max(x2 - x1 + 1, 1);
    int rh = max(y2 - y1 + 1, 1);

    const float* fl = featT + 4 * lane;     // lane's channel quad base

    // wave w handles bins pq = w, w+8, ... : bounds are wave-uniform
    for (int pq = wave; pq < NBIN; pq += 8) {
        int p = pq / PP, q = pq % PP;       // magic-mul, non-negative
        int hs = min(max(p * rh / PP + y1, 0), HH);
        int he = min(max(((p + 1) * rh + PP - 1) / PP + y1, 0), HH);
        int ws = min(max(q * rw / PP + x1, 0), WW);
        int we = min(max(((q + 1) * rw + PP - 1) / PP + x1, 0), WW);

        float4 m = make_float4(-INFINITY, -INFINITY, -INFINITY, -INFINITY);
        for (int h = hs; h < he; ++h) {
            const float* base = fl + h * (WW * CC);
            for (int w = ws; w < we; ++w) {
                float4 v = *(const float4*)(base + w * CC);  // 1 KB/wave-load
                m.x = fmaxf(m.x, v.x);
                m.y = fmaxf(m.y, v.y);
                m.z = fmaxf(m.z, v.z);
                m.w = fmaxf(m.w, v.w);
            }
        }
        if ((he <= hs) || (we <= ws))
            m = make_float4(0.0f, 0.0f, 0.0f, 0.0f);

        int base = lane * 49 + pq;
        res2[base           ] = m.x;        // j=0
        res2[base + 1 * 3136] = m.y;        // j=1  (3136 = 64*49)
        res2[base + 2 * 3136] = m.z;        // j=2
        res2[base + 3 * 3136] = m.w;        // j=3
    }
    __syncthreads();

    // writeback: consecutive tids -> consecutive out idx (coalesced) and
    // consecutive LDS addrs (conflict-free)
    float* on = out + n * OUT_PER_BOX;
    for (int i = tid; i < OUT_PER_BOX; i += 512) {
        int c = i / 49, pq = i % 49;
        on[i] = res2[((c & 3) * 64 + (c >> 2)) * 49 + pq];
    }
}

extern "C" void kernel_launch(void* const* d_in, const int* in_sizes, int n_in,
                              void* d_out, int out_size, void* d_ws, size_t ws_size,
                              hipStream_t stream)
{
    const float* feat  = (const float*)d_in[0];
    const float* boxes = (const float*)d_in[1];
    float* out = (float*)d_out;

    float* featT = (float*)d_ws;            // 2,560,000 B needed
    transpose_kernel<<<40 * 4, 256, 0, stream>>>(feat, featT);
    pool_kernel<<<NBOX, 512, 0, stream>>>(featT, boxes, out);
}